// Round 1
// baseline (1207.910 us; speedup 1.0000x reference)
//
#include <hip/hip_runtime.h>
#include <math.h>

#define NB 2
#define NN1 4096
#define NN2 8192
#define NPART 8
#define LEAKK 0.1f

__device__ __forceinline__ float leaky_(float x) { return fmaxf(x, LEAKK * x); }
__device__ __forceinline__ float sigm_(float x) { return 1.0f / (1.0f + __expf(-x)); }

// insert (d,i) into sorted-ascending-(d,i)-lex list of 8 kept in registers
__device__ __forceinline__ void ins8_(float d, int i, float* ld, int* li) {
  bool better = (d < ld[7]) || (d == ld[7] && i < li[7]);
  if (better) {
#pragma unroll
    for (int j = 0; j < 8; ++j) {
      bool lt = (d < ld[j]) || (d == ld[j] && i < li[j]);
      if (lt) { float td = ld[j]; int ti = li[j]; ld[j] = d; li[j] = i; d = td; i = ti; }
    }
  }
}

// merge two sorted 8-lists, keep first 8 (result in a)
__device__ __forceinline__ void merge8_(float* ad, int* ai, float* bd, int* bi) {
  float rd[8]; int ri[8];
#pragma unroll
  for (int s = 0; s < 8; ++s) {
    bool ta = (ad[0] < bd[0]) || (ad[0] == bd[0] && ai[0] < bi[0]);
    rd[s] = ta ? ad[0] : bd[0];
    ri[s] = ta ? ai[0] : bi[0];
#pragma unroll
    for (int j = 0; j < 7; ++j) {
      ad[j] = ta ? ad[j + 1] : ad[j];
      ai[j] = ta ? ai[j + 1] : ai[j];
      bd[j] = ta ? bd[j] : bd[j + 1];
      bi[j] = ta ? bi[j] : bi[j + 1];
    }
  }
#pragma unroll
  for (int j = 0; j < 8; ++j) { ad[j] = rd[j]; ai[j] = ri[j]; }
}

// ---------------- K0: transpose all 15 weight matrices into ws ----------------
__global__ void prep_w_kernel(const float* s0, const float* s1, const float* s2,
                              const float* s3, const float* s4, const float* s5,
                              const float* s6, const float* s7, const float* s8,
                              const float* s9, const float* s10, const float* s11,
                              const float* s12, const float* s13, const float* s14,
                              float* wt) {
  const float* srcs[15] = {s0, s1, s2, s3, s4, s5, s6, s7, s8, s9, s10, s11, s12, s13, s14};
  int bid = blockIdx.x;
  const float* src = srcs[bid];
  int cols = (bid < 6) ? 64 : (((bid - 6) % 3 == 0) ? 3 : 64);
  float* dst = wt + bid * 4096;
  for (int e = threadIdx.x; e < 64 * cols; e += blockDim.x) {
    int o = e / cols, c = e - o * cols;
    dst[c * 64 + o] = src[e];
  }
}

// ---------------- K1: transpose+normalize knn features, pack xyz+|x|^2 ----------------
__global__ __launch_bounds__(64) void prep_side_kernel(const float* knn, const float* xyz,
                                                       float* fdst, float* xdst, int N) {
  __shared__ float T[64 * 65];
  __shared__ float rs[64];
  int b = blockIdx.y;
  int n0 = blockIdx.x * 64;
  int l = threadIdx.x;
  const float* kb = knn + (size_t)b * 64 * N + n0;
  for (int c = 0; c < 64; ++c) T[c * 65 + l] = kb[(size_t)c * N + l];
  __syncthreads();
  float s = 0.f;
  for (int c = 0; c < 64; ++c) { float v = T[c * 65 + l]; s += v * v; }
  rs[l] = 1.0f / sqrtf(s + 1e-8f);
  __syncthreads();
  for (int i = 0; i < 64; ++i)
    fdst[(size_t)(b * N + n0 + i) * 64 + l] = T[l * 65 + i] * rs[i];
  const float* xb = xyz + (size_t)b * 3 * N + n0;
  float x = xb[l], y = xb[N + l], z = xb[2 * N + l];
  ((float4*)xdst)[b * N + n0 + l] = make_float4(x, y, z, x * x + y * y + z * z);
}

// ---------------- K2: three fused 1x1 conv matvecs ----------------
__global__ __launch_bounds__(256) void fuse_kernel(const float* pts, const float* wt0,
                                                   const float* wt1, const float* wt2,
                                                   float* d0, float* d1, float* d2, int N) {
  int b = blockIdx.y;
  int w = threadIdx.x >> 6, l = threadIdx.x & 63;
  int n = blockIdx.x * 4 + w;
  const float* pb = pts + (size_t)b * 64 * N + n;
  float a0 = 0.f, a1 = 0.f, a2 = 0.f;
  for (int c = 0; c < 64; ++c) {
    float p = pb[(size_t)c * N];
    a0 += p * wt0[c * 64 + l];
    a1 += p * wt1[c * 64 + l];
    a2 += p * wt2[c * 64 + l];
  }
  size_t ob = (size_t)(b * N + n) * 64 + l;
  d0[ob] = a0; d1[ob] = a1; d2[ob] = a2;
}

// ---------------- K3: dual-metric partitioned KNN ----------------
__global__ __launch_bounds__(256) void knn_kernel(const float* f1n, const float* f2n,
                                                  const float* x1t, const float* x2t,
                                                  float* pd, int* pi) {
  __shared__ float f1t[4096];
  __shared__ float f2t[4096];
  __shared__ float x1s[256];
  __shared__ float x2s[256];
  __shared__ float dcs[64 * 65];
  __shared__ float des[64 * 65];

  int t = threadIdx.x;
  int n0 = blockIdx.x * 64;
  int part = blockIdx.y;
  int b = blockIdx.z;
  int row = t & 63, q = t >> 6;

  const float* f1row = f1n + (size_t)(b * NN1 + n0 + row) * 64;
#pragma unroll
  for (int pass = 0; pass < 4; ++pass) {
    int c0 = pass * 16 + q * 4;
    float4 v = *(const float4*)(f1row + c0);
    f1t[(c0 + 0) * 64 + row] = v.x;
    f1t[(c0 + 1) * 64 + row] = v.y;
    f1t[(c0 + 2) * 64 + row] = v.z;
    f1t[(c0 + 3) * 64 + row] = v.w;
  }
  if (t < 64) ((float4*)x1s)[t] = ((const float4*)x1t)[b * NN1 + n0 + t];

  float cd[8], ed[8]; int ci[8], ei[8];
#pragma unroll
  for (int j = 0; j < 8; ++j) { cd[j] = INFINITY; ed[j] = INFINITY; ci[j] = 0x7fffffff; ei[j] = 0x7fffffff; }

  int ty = t >> 4, tx = t & 15;
  int r0 = ty * 4, c0g = tx * 4;

  for (int ch = 0; ch < 16; ++ch) {
    int cbase = part * (NN2 / NPART) + ch * 64;
    const float* f2row = f2n + (size_t)(b * NN2 + cbase + row) * 64;
#pragma unroll
    for (int pass = 0; pass < 4; ++pass) {
      int c0 = pass * 16 + q * 4;
      float4 v = *(const float4*)(f2row + c0);
      f2t[(c0 + 0) * 64 + row] = v.x;
      f2t[(c0 + 1) * 64 + row] = v.y;
      f2t[(c0 + 2) * 64 + row] = v.z;
      f2t[(c0 + 3) * 64 + row] = v.w;
    }
    if (t < 64) ((float4*)x2s)[t] = ((const float4*)x2t)[b * NN2 + cbase + t];
    __syncthreads();

    float acc[4][4];
#pragma unroll
    for (int i = 0; i < 4; ++i)
#pragma unroll
      for (int j = 0; j < 4; ++j) acc[i][j] = 0.f;

    for (int k = 0; k < 64; ++k) {
      float4 a = *(const float4*)&f1t[k * 64 + r0];
      float4 bb = *(const float4*)&f2t[k * 64 + c0g];
      acc[0][0] += a.x * bb.x; acc[0][1] += a.x * bb.y; acc[0][2] += a.x * bb.z; acc[0][3] += a.x * bb.w;
      acc[1][0] += a.y * bb.x; acc[1][1] += a.y * bb.y; acc[1][2] += a.y * bb.z; acc[1][3] += a.y * bb.w;
      acc[2][0] += a.z * bb.x; acc[2][1] += a.z * bb.y; acc[2][2] += a.z * bb.z; acc[2][3] += a.z * bb.w;
      acc[3][0] += a.w * bb.x; acc[3][1] += a.w * bb.y; acc[3][2] += a.w * bb.z; acc[3][3] += a.w * bb.w;
    }

#pragma unroll
    for (int i = 0; i < 4; ++i) {
      float4 xa = ((float4*)x1s)[r0 + i];
#pragma unroll
      for (int j = 0; j < 4; ++j) {
        float4 xb = ((float4*)x2s)[c0g + j];
        float d3 = xa.w + xb.w - 2.f * (xa.x * xb.x + xa.y * xb.y + xa.z * xb.z);
        dcs[(r0 + i) * 65 + (c0g + j)] = 1.0f - acc[i][j];
        des[(r0 + i) * 65 + (c0g + j)] = d3;
      }
    }
    __syncthreads();

    {
      int srow = t & 63, w = t >> 6;
#pragma unroll
      for (int s = 0; s < 16; ++s) {
        int c = w * 16 + s;
        int gi = cbase + c;
        ins8_(dcs[srow * 65 + c], gi, cd, ci);
        ins8_(des[srow * 65 + c], gi, ed, ei);
      }
    }
    __syncthreads();
  }

  // in-block merge of the 4 per-wave lists per row
  {
    int srow = t & 63, w = t >> 6;
    float* Lcd = dcs; float* Led = des;
    int* Lci = (int*)f2t; int* Lei = (int*)f1t;
#pragma unroll
    for (int j = 0; j < 8; ++j) {
      Lcd[srow * 33 + w * 8 + j] = cd[j];
      Lci[srow * 33 + w * 8 + j] = ci[j];
      Led[srow * 33 + w * 8 + j] = ed[j];
      Lei[srow * 33 + w * 8 + j] = ei[j];
    }
    __syncthreads();
    if (t < 128) {
      int typ = t >> 6, r = t & 63;
      const float* Ld = typ ? Led : Lcd;
      const int* Li = typ ? Lei : Lci;
      float a0d[8], a1d[8], a2d[8], a3d[8];
      int a0i[8], a1i[8], a2i[8], a3i[8];
#pragma unroll
      for (int j = 0; j < 8; ++j) {
        a0d[j] = Ld[r * 33 + 0 + j];  a0i[j] = Li[r * 33 + 0 + j];
        a1d[j] = Ld[r * 33 + 8 + j];  a1i[j] = Li[r * 33 + 8 + j];
        a2d[j] = Ld[r * 33 + 16 + j]; a2i[j] = Li[r * 33 + 16 + j];
        a3d[j] = Ld[r * 33 + 24 + j]; a3i[j] = Li[r * 33 + 24 + j];
      }
      merge8_(a0d, a0i, a1d, a1i);
      merge8_(a2d, a2i, a3d, a3i);
      merge8_(a0d, a0i, a2d, a2i);
      size_t base = ((size_t)(b * NPART + part) * NN1 + n0 + r) * 16 + typ * 8;
#pragma unroll
      for (int j = 0; j < 8; ++j) { pd[base + j] = a0d[j]; pi[base + j] = a0i[j]; }
    }
  }
}

// ---------------- K4: merge the NPART partial lists -> final idx ----------------
__device__ __forceinline__ void loadlist_(const float* pd, const int* pi, int b, int p, int n1,
                                          int typ, float* d, int* i) {
  size_t base = ((size_t)(b * NPART + p) * NN1 + n1) * 16 + typ * 8;
#pragma unroll
  for (int j = 0; j < 8; ++j) { d[j] = pd[base + j]; i[j] = pi[base + j]; }
}

__global__ __launch_bounds__(256) void merge_parts_kernel(const float* pd, const int* pi, int* idxb) {
  int g = blockIdx.x * blockDim.x + threadIdx.x;
  if (g >= NB * NN1) return;
  int b = g / NN1, n1 = g - b * NN1;
#pragma unroll
  for (int typ = 0; typ < 2; ++typ) {
    float td[8], ud[8], md[8], vd[8];
    int ti[8], ui[8], mi[8], vi[8];
    loadlist_(pd, pi, b, 0, n1, typ, td, ti);
    loadlist_(pd, pi, b, 1, n1, typ, ud, ui);
    merge8_(td, ti, ud, ui);                 // 01
    loadlist_(pd, pi, b, 2, n1, typ, md, mi);
    loadlist_(pd, pi, b, 3, n1, typ, ud, ui);
    merge8_(md, mi, ud, ui);                 // 23
    merge8_(td, ti, md, mi);                 // 0123
    loadlist_(pd, pi, b, 4, n1, typ, md, mi);
    loadlist_(pd, pi, b, 5, n1, typ, ud, ui);
    merge8_(md, mi, ud, ui);                 // 45
    loadlist_(pd, pi, b, 6, n1, typ, vd, vi);
    loadlist_(pd, pi, b, 7, n1, typ, ud, ui);
    merge8_(vd, vi, ud, ui);                 // 67
    merge8_(md, mi, vd, vi);                 // 4567
    merge8_(td, ti, md, mi);                 // final
    size_t ob = (size_t)g * 16 + typ * 8;
#pragma unroll
    for (int j = 0; j < 8; ++j) idxb[ob + j] = ti[j];
  }
}

// ---------------- K5: fused GRU mapping (one wave per (b,n1)) ----------------
__global__ __launch_bounds__(256) void gru_kernel(
    const int* idxb, const float* x1t, const float* x2t,
    const float* p1r, const float* p1ro, const float* p1z,
    const float* p2r, const float* p2ro, const float* p2z,
    const float* wt,
    const float* br0, const float* br1, const float* br2,
    const float* bz0, const float* bz1, const float* bz2,
    const float* bh0, const float* bh1, const float* bh2,
    float* out) {
  __shared__ float dxs[4][16 * 4];
  __shared__ float Vs[4][64];
  __shared__ float Gs[4][16 * 64];
  __shared__ float As[4][16 * 64];
  __shared__ float Bs[4][16 * 64];
  __shared__ float R3s[4][16 * 64];
  __shared__ int idxs[4][16];

  int t = threadIdx.x;
  int w = t >> 6, l = t & 63;
  int b = blockIdx.y;
  int n1i = blockIdx.x * 4 + w;
  int rowbase = b * NN1 + n1i;

  float* dx = dxs[w]; float* V = Vs[w]; float* G = Gs[w];
  float* A = As[w]; float* Bb = Bs[w]; float* R3 = R3s[w];
  int* idxw = idxs[w];

  if (l < 16) idxw[l] = idxb[(size_t)rowbase * 16 + l];
  __syncthreads();
  if (l < 16) {
    float4 x1v = ((const float4*)x1t)[rowbase];
    float4 x2v = ((const float4*)x2t)[b * NN2 + idxw[l]];
    dx[l * 4 + 0] = x2v.x - x1v.x;
    dx[l * 4 + 1] = x2v.y - x1v.y;
    dx[l * 4 + 2] = x2v.z - x1v.z;
  }
  float pr  = p1r[(size_t)rowbase * 64 + l];
  float pro = p1ro[(size_t)rowbase * 64 + l];
  float pz  = p1z[(size_t)rowbase * 64 + l];
  __syncthreads();

  const float* Wr0t = wt + 6 * 4096;
  const float* Wr1t = wt + 7 * 4096;
  const float* Wr2t = wt + 8 * 4096;
  const float* Wz0t = wt + 9 * 4096;
  const float* Wz1t = wt + 10 * 4096;
  const float* Wz2t = wt + 11 * 4096;
  const float* Wh0t = wt + 12 * 4096;
  const float* Wh1t = wt + 13 * 4096;
  const float* Wh2t = wt + 14 * 4096;

  float wv[64];

  // ---- r branch ----
  for (int k = 0; k < 16; ++k)
    G[k * 64 + l] = p2r[((size_t)b * NN2 + idxw[k]) * 64 + l];
  __syncthreads();
  {
    float w0 = Wr0t[l], w1 = Wr0t[64 + l], w2 = Wr0t[128 + l];
    float b0 = br0[l];
#pragma unroll
    for (int k = 0; k < 16; ++k) {
      float pre = b0 + pr + G[k * 64 + l]
                + w0 * dx[k * 4 + 0] + w1 * dx[k * 4 + 1] + w2 * dx[k * 4 + 2];
      A[k * 64 + l] = leaky_(pre);
    }
  }
  __syncthreads();
#pragma unroll
  for (int c = 0; c < 64; ++c) wv[c] = Wr1t[c * 64 + l];
  {
    float b1 = br1[l];
    for (int k = 0; k < 16; ++k) {
      float acc = b1;
#pragma unroll
      for (int c4 = 0; c4 < 16; ++c4) {
        float4 a4 = *(const float4*)&A[k * 64 + c4 * 4];
        acc += wv[c4 * 4 + 0] * a4.x + wv[c4 * 4 + 1] * a4.y
             + wv[c4 * 4 + 2] * a4.z + wv[c4 * 4 + 3] * a4.w;
      }
      Bb[k * 64 + l] = leaky_(acc);
    }
  }
  __syncthreads();
#pragma unroll
  for (int c = 0; c < 64; ++c) wv[c] = Wr2t[c * 64 + l];
  {
    float b2 = br2[l];
    for (int k = 0; k < 16; ++k) {
      float acc = b2;
#pragma unroll
      for (int c4 = 0; c4 < 16; ++c4) {
        float4 a4 = *(const float4*)&Bb[k * 64 + c4 * 4];
        acc += wv[c4 * 4 + 0] * a4.x + wv[c4 * 4 + 1] * a4.y
             + wv[c4 * 4 + 2] * a4.z + wv[c4 * 4 + 3] * a4.w;
      }
      R3[k * 64 + l] = sigm_(acc);
    }
  }
  __syncthreads();

  // ---- z branch ----
  for (int k = 0; k < 16; ++k)
    G[k * 64 + l] = p2ro[((size_t)b * NN2 + idxw[k]) * 64 + l];
  __syncthreads();
  {
    float w0 = Wz0t[l], w1 = Wz0t[64 + l], w2 = Wz0t[128 + l];
    float b0 = bz0[l];
#pragma unroll
    for (int k = 0; k < 16; ++k) {
      float pre = b0 + pz + G[k * 64 + l]
                + w0 * dx[k * 4 + 0] + w1 * dx[k * 4 + 1] + w2 * dx[k * 4 + 2];
      A[k * 64 + l] = leaky_(pre);
    }
  }
  __syncthreads();
#pragma unroll
  for (int c = 0; c < 64; ++c) wv[c] = Wz1t[c * 64 + l];
  {
    float b1 = bz1[l];
    float zm = -INFINITY;
    for (int k = 0; k < 16; ++k) {
      float acc = b1;
#pragma unroll
      for (int c4 = 0; c4 < 16; ++c4) {
        float4 a4 = *(const float4*)&A[k * 64 + c4 * 4];
        acc += wv[c4 * 4 + 0] * a4.x + wv[c4 * 4 + 1] * a4.y
             + wv[c4 * 4 + 2] * a4.z + wv[c4 * 4 + 3] * a4.w;
      }
      zm = fmaxf(zm, leaky_(acc));
    }
    V[l] = zm;
  }
  __syncthreads();
  float z3;
  {
    float acc = bz2[l];
#pragma unroll
    for (int c4 = 0; c4 < 16; ++c4) {
      float4 v4 = *(const float4*)&V[c4 * 4];
      acc += Wz2t[(c4 * 4 + 0) * 64 + l] * v4.x + Wz2t[(c4 * 4 + 1) * 64 + l] * v4.y
           + Wz2t[(c4 * 4 + 2) * 64 + l] * v4.z + Wz2t[(c4 * 4 + 3) * 64 + l] * v4.w;
    }
    z3 = sigm_(acc);
  }
  __syncthreads();

  // ---- h branch ----
  for (int k = 0; k < 16; ++k)
    G[k * 64 + l] = p2z[((size_t)b * NN2 + idxw[k]) * 64 + l];
  __syncthreads();
  {
    float w0 = Wh0t[l], w1 = Wh0t[64 + l], w2 = Wh0t[128 + l];
    float b0 = bh0[l];
#pragma unroll
    for (int k = 0; k < 16; ++k) {
      float pre = b0 + R3[k * 64 + l] * pro + G[k * 64 + l]
                + w0 * dx[k * 4 + 0] + w1 * dx[k * 4 + 1] + w2 * dx[k * 4 + 2];
      A[k * 64 + l] = leaky_(pre);
    }
  }
  __syncthreads();
#pragma unroll
  for (int c = 0; c < 64; ++c) wv[c] = Wh1t[c * 64 + l];
  {
    float b1 = bh1[l];
    float hm = -INFINITY;
    for (int k = 0; k < 16; ++k) {
      float acc = b1;
#pragma unroll
      for (int c4 = 0; c4 < 16; ++c4) {
        float4 a4 = *(const float4*)&A[k * 64 + c4 * 4];
        acc += wv[c4 * 4 + 0] * a4.x + wv[c4 * 4 + 1] * a4.y
             + wv[c4 * 4 + 2] * a4.z + wv[c4 * 4 + 3] * a4.w;
      }
      hm = fmaxf(hm, leaky_(acc));
    }
    V[l] = hm;
  }
  __syncthreads();
  float h3;
  {
    float acc = bh2[l];
#pragma unroll
    for (int c4 = 0; c4 < 16; ++c4) {
      float4 v4 = *(const float4*)&V[c4 * 4];
      acc += Wh2t[(c4 * 4 + 0) * 64 + l] * v4.x + Wh2t[(c4 * 4 + 1) * 64 + l] * v4.y
           + Wh2t[(c4 * 4 + 2) * 64 + l] * v4.z + Wh2t[(c4 * 4 + 3) * 64 + l] * v4.w;
    }
    h3 = leaky_(acc);
  }

  out[((size_t)b * 64 + l) * NN1 + n1i] = (1.0f - z3) * pro + z3 * h3;
}

extern "C" void kernel_launch(void* const* d_in, const int* in_sizes, int n_in,
                              void* d_out, int out_size, void* d_ws, size_t ws_size,
                              hipStream_t stream) {
  (void)in_sizes; (void)n_in; (void)out_size; (void)ws_size;
  const float* xyz1    = (const float*)d_in[0];
  const float* xyz2    = (const float*)d_in[1];
  const float* points1 = (const float*)d_in[2];
  const float* points2 = (const float*)d_in[3];
  const float* knn1    = (const float*)d_in[4];
  const float* knn2    = (const float*)d_in[5];
  const float* Wfr   = (const float*)d_in[6];
  const float* Wfro  = (const float*)d_in[7];
  const float* Wfz   = (const float*)d_in[8];
  const float* Wfr2  = (const float*)d_in[9];
  const float* Wfro2 = (const float*)d_in[10];
  const float* Wfz2  = (const float*)d_in[11];
  const float* Wr0 = (const float*)d_in[12]; const float* br0 = (const float*)d_in[13];
  const float* Wr1 = (const float*)d_in[14]; const float* br1 = (const float*)d_in[15];
  const float* Wr2 = (const float*)d_in[16]; const float* br2 = (const float*)d_in[17];
  const float* Wz0 = (const float*)d_in[18]; const float* bz0 = (const float*)d_in[19];
  const float* Wz1 = (const float*)d_in[20]; const float* bz1 = (const float*)d_in[21];
  const float* Wz2 = (const float*)d_in[22]; const float* bz2 = (const float*)d_in[23];
  const float* Wh0 = (const float*)d_in[24]; const float* bh0 = (const float*)d_in[25];
  const float* Wh1 = (const float*)d_in[26]; const float* bh1 = (const float*)d_in[27];
  const float* Wh2 = (const float*)d_in[28]; const float* bh2 = (const float*)d_in[29];

  float* W = (float*)d_ws;
  size_t o = 0;
  float* f1n = W + o; o += (size_t)NB * NN1 * 64;
  float* f2n = W + o; o += (size_t)NB * NN2 * 64;
  float* x1t = W + o; o += (size_t)NB * NN1 * 4;
  float* x2t = W + o; o += (size_t)NB * NN2 * 4;
  float* p1r = W + o; o += (size_t)NB * NN1 * 64;
  float* p1ro = W + o; o += (size_t)NB * NN1 * 64;
  float* p1z = W + o; o += (size_t)NB * NN1 * 64;
  float* p2r = W + o; o += (size_t)NB * NN2 * 64;
  float* p2ro = W + o; o += (size_t)NB * NN2 * 64;
  float* p2z = W + o; o += (size_t)NB * NN2 * 64;
  float* wt = W + o; o += (size_t)15 * 4096;
  float* pd = W + o; o += (size_t)NB * NPART * NN1 * 16;
  int* pi = (int*)(W + o); o += (size_t)NB * NPART * NN1 * 16;
  int* idxb = (int*)(W + o); o += (size_t)NB * NN1 * 16;

  float* out = (float*)d_out;

  hipLaunchKernelGGL(prep_w_kernel, dim3(15), dim3(256), 0, stream,
                     Wfr, Wfro, Wfz, Wfr2, Wfro2, Wfz2,
                     Wr0, Wr1, Wr2, Wz0, Wz1, Wz2, Wh0, Wh1, Wh2, wt);
  hipLaunchKernelGGL(prep_side_kernel, dim3(NN1 / 64, NB), dim3(64), 0, stream,
                     knn1, xyz1, f1n, x1t, NN1);
  hipLaunchKernelGGL(prep_side_kernel, dim3(NN2 / 64, NB), dim3(64), 0, stream,
                     knn2, xyz2, f2n, x2t, NN2);
  hipLaunchKernelGGL(fuse_kernel, dim3(NN1 / 4, NB), dim3(256), 0, stream,
                     points1, wt + 0 * 4096, wt + 1 * 4096, wt + 2 * 4096,
                     p1r, p1ro, p1z, NN1);
  hipLaunchKernelGGL(fuse_kernel, dim3(NN2 / 4, NB), dim3(256), 0, stream,
                     points2, wt + 3 * 4096, wt + 4 * 4096, wt + 5 * 4096,
                     p2r, p2ro, p2z, NN2);
  hipLaunchKernelGGL(knn_kernel, dim3(NN1 / 64, NPART, NB), dim3(256), 0, stream,
                     f1n, f2n, x1t, x2t, pd, pi);
  hipLaunchKernelGGL(merge_parts_kernel, dim3((NB * NN1 + 255) / 256), dim3(256), 0, stream,
                     pd, pi, idxb);
  hipLaunchKernelGGL(gru_kernel, dim3(NN1 / 4, NB), dim3(256), 0, stream,
                     idxb, x1t, x2t, p1r, p1ro, p1z, p2r, p2ro, p2z, wt,
                     br0, br1, br2, bz0, bz1, bz2, bh0, bh1, bh2, out);
}